// Round 17
// baseline (2348.870 us; speedup 1.0000x reference)
//
#include <hip/hip_runtime.h>
#include <cstdint>

typedef unsigned short u16;
typedef __attribute__((ext_vector_type(8))) short bf16x8;
typedef __attribute__((ext_vector_type(4))) float f32x4;

#define DEV static __device__ __forceinline__

// ---- problem dims ----
#define BB 32
#define PP 196
#define DD 768
#define HH 12
#define HDD 64
#define SS 197
#define NTOK 6304    // 32*197
#define NTOKX 6272   // 32*196
#define NCLS 1000
#define DD4 3072
#define KPAD 224     // padded attention K (197 -> 224 = 7*32)
#define NBH 384      // 32*12
#define NLAY 8

DEV u16 f2bf(float f){ unsigned u=__float_as_uint(f); u += 0x7FFFu + ((u>>16)&1u); return (u16)(u>>16); }
DEV float bf2f(u16 u){ return __uint_as_float(((unsigned)u)<<16); }

// gelu via A&S 7.1.26 erf poly (|err| <= 1.5e-7, below bf16 rounding).
DEV float gelu_f(float x){
  float z  = 0.70710678118654752f * x;
  float az = fabsf(z);
  float t  = __builtin_amdgcn_rcpf(fmaf(0.3275911f, az, 1.f));
  float poly = t*(0.254829592f + t*(-0.284496736f + t*(1.421413741f + t*(-1.453152027f + t*1.061405429f))));
  float e  = __expf(-az*az);
  float erf_abs = 1.f - poly*e;
  float erfv = copysignf(erf_abs, x);
  return 0.5f * x * (1.f + erfv);
}

typedef __attribute__((address_space(1))) void gas1;
typedef __attribute__((address_space(3))) void las3;

DEV void gld16(const void* g, void* l){
  __builtin_amdgcn_global_load_lds((gas1*)(uintptr_t)g, (las3*)(unsigned)(uintptr_t)l, 16, 0, 0);
}

struct __align__(8) u16x4 { u16 x,y,z,w; };

// ================= small kernels =================

// Reference parity is on the POSITION index (rows), not the feature index.
__global__ void pos_kernel(float* __restrict__ pos){
  int idx = blockIdx.x*256 + threadIdx.x;
  if (idx >= PP*DD) return;
  int p = idx / DD, j = idx - p*DD;
  int odd = p & 1;
  float e = ((float)j - (float)odd) * (1.0f/(float)DD);
  float arg = (float)p / powf(10000.0f, e);
  pos[idx] = odd ? cosf(arg) : sinf(arg);
}

__global__ void f32_to_bf16_kernel(const float* __restrict__ in, u16* __restrict__ out, int n4){
  int i = blockIdx.x*256 + threadIdx.x;
  if (i >= n4) return;
  float4 v = reinterpret_cast<const float4*>(in)[i];
  u16x4 o = { f2bf(v.x), f2bf(v.y), f2bf(v.z), f2bf(v.w) };
  reinterpret_cast<u16x4*>(out)[i] = o;
}

__global__ void clstok_kernel(const float* __restrict__ vcls, float* __restrict__ h){
  int b = blockIdx.x;
  for (int i = threadIdx.x; i < DD; i += 256)
    h[(size_t)b*SS*DD + i] = vcls[i];
}

// transpose f32 (R x C) -> bf16 (C x R), batched over blockIdx.z. block (32,8)
__global__ void transpose_kernel(const float* __restrict__ in, u16* __restrict__ out, int R, int C){
  __shared__ float tile[32][33];
  int bx = blockIdx.x*32, by = blockIdx.y*32;
  size_t zoff = (size_t)blockIdx.z * R * C;
  const float* src = in + zoff;
  u16* dst = out + zoff;
  int tx = threadIdx.x, ty = threadIdx.y;
  #pragma unroll
  for (int q=0;q<4;q++)
    tile[ty + q*8][tx] = src[(size_t)(by + ty + q*8)*C + bx + tx];
  __syncthreads();
  #pragma unroll
  for (int q=0;q<4;q++)
    dst[(size_t)(bx + ty + q*8)*R + by + tx] = f2bf(tile[tx][ty + q*8]);
}

// LN stats only: one wave per token -> (mean, rstd)
__global__ void ln_stats_kernel(const float* __restrict__ h, float2* __restrict__ stats){
  int t = blockIdx.x*4 + (threadIdx.x>>6);
  int lane = threadIdx.x & 63;
  const float4* src = reinterpret_cast<const float4*>(h + (size_t)t*DD);
  float s = 0.f, s2 = 0.f;
  #pragma unroll
  for (int p=0;p<3;p++){
    float4 v = src[p*64 + lane];
    s  += v.x + v.y + v.z + v.w;
    s2 += v.x*v.x + v.y*v.y + v.z*v.z + v.w*v.w;
  }
  #pragma unroll
  for (int o=32;o>0;o>>=1){ s += __shfl_xor(s,o); s2 += __shfl_xor(s2,o); }
  if (lane == 0){
    float mean = s * (1.f/(float)DD);
    float rstd = rsqrtf(s2*(1.f/(float)DD) - mean*mean + 1e-5f);
    stats[t] = make_float2(mean, rstd);
  }
}

// LayerNorm: one wave per token. h f32 -> xn bf16 (used for ln2 -> fc1 input)
__global__ void ln_kernel(const float* __restrict__ h, const float* __restrict__ g,
                          const float* __restrict__ b, u16* __restrict__ xn){
  int t = blockIdx.x*4 + (threadIdx.x>>6);
  int lane = threadIdx.x & 63;
  const float4* src = reinterpret_cast<const float4*>(h + (size_t)t*DD);
  float4 xv[3];
  float s = 0.f, s2 = 0.f;
  #pragma unroll
  for (int p=0;p<3;p++){
    xv[p] = src[p*64 + lane];
    s  += xv[p].x + xv[p].y + xv[p].z + xv[p].w;
    s2 += xv[p].x*xv[p].x + xv[p].y*xv[p].y + xv[p].z*xv[p].z + xv[p].w*xv[p].w;
  }
  #pragma unroll
  for (int o=32;o>0;o>>=1){ s += __shfl_xor(s,o); s2 += __shfl_xor(s2,o); }
  float mean = s * (1.f/(float)DD);
  float rstd = rsqrtf(s2*(1.f/(float)DD) - mean*mean + 1e-5f);
  #pragma unroll
  for (int p=0;p<3;p++){
    int base = p*256 + lane*4;
    u16x4 o4 = { f2bf((xv[p].x-mean)*rstd*g[base+0]+b[base+0]),
                 f2bf((xv[p].y-mean)*rstd*g[base+1]+b[base+1]),
                 f2bf((xv[p].z-mean)*rstd*g[base+2]+b[base+2]),
                 f2bf((xv[p].w-mean)*rstd*g[base+3]+b[base+3]) };
    *reinterpret_cast<u16x4*>(&xn[(size_t)t*DD + base]) = o4;
  }
}

// ===== main 128x128 bf16 GEMM (round-13 proven config: 68 us) — emb & fc2 =====
template<int EPI>
__global__ __launch_bounds__(256) void gemm_bf16(
    const u16* __restrict__ A, const u16* __restrict__ BT, int M, int K,
    int nbm, int nbn,
    const float* __restrict__ bias, const float* __restrict__ pos,
    float* __restrict__ Hout, u16* __restrict__ Bout)
{
  __shared__ __align__(16) u16 As[2][128*32];
  __shared__ __align__(16) u16 Bs[2][128*32];
  const int tid = threadIdx.x;
  const int wave = tid>>6, lane = tid&63;

  // XCD-bijective chunk swizzle (m204).
  const int nwg = nbm*nbn;
  const int wg = blockIdx.x;
  const int xcd = wg & 7, ii = wg >> 3;
  const int q8 = nwg >> 3, r8 = nwg & 7;
  const int lin = (xcd < r8 ? xcd*(q8+1) : r8*(q8+1) + (xcd-r8)*q8) + ii;
  const int bm = lin / nbn, bn = lin - bm*nbn;

  const int wr = wave>>1, wc = wave&1;

  f32x4 acc[4][4] = {};

  const int lr = lane>>2;
  const int lc = ((lane&3) ^ ((lane>>3)&3)) * 8;   // permuted source chunk (T2)
  int ar0 = bm*128 + (wave*2+0)*16 + lr; if (ar0 > M-1) ar0 = M-1;
  int ar1 = bm*128 + (wave*2+1)*16 + lr; if (ar1 > M-1) ar1 = M-1;
  const u16* aS0 = A + (size_t)ar0*K + lc;
  const u16* aS1 = A + (size_t)ar1*K + lc;
  const u16* bS0 = BT + (size_t)(bn*128 + (wave*2+0)*16 + lr)*K + lc;
  const u16* bS1 = BT + (size_t)(bn*128 + (wave*2+1)*16 + lr)*K + lc;
  const int d0 = (wave*2+0)*512;
  const int d1 = (wave*2+1)*512;

  auto stage = [&](int buf, int kt){
    gld16(aS0 + kt, &As[buf][d0]);
    gld16(aS1 + kt, &As[buf][d1]);
    gld16(bS0 + kt, &Bs[buf][d0]);
    gld16(bS1 + kt, &Bs[buf][d1]);
  };
  const int rchunk = ((lane>>4) ^ (((lane&15)>>1)&3)) * 8;
  auto compute = [&](int buf){
    bf16x8 af[4], bfv[4];
    #pragma unroll
    for (int i=0;i<4;i++)
      af[i] = *reinterpret_cast<const bf16x8*>(&As[buf][(wr*64 + i*16 + (lane&15))*32 + rchunk]);
    #pragma unroll
    for (int j=0;j<4;j++)
      bfv[j] = *reinterpret_cast<const bf16x8*>(&Bs[buf][(wc*64 + j*16 + (lane&15))*32 + rchunk]);
    #pragma unroll
    for (int i=0;i<4;i++)
      #pragma unroll
      for (int j=0;j<4;j++)
        acc[i][j] = __builtin_amdgcn_mfma_f32_16x16x32_bf16(af[i], bfv[j], acc[i][j], 0, 0, 0);
  };

  const int NT = K >> 5;
  stage(0, 0);
  int cur = 0;
  for (int t = 0; t < NT; ++t){
    if (t+1 < NT){
      stage(cur^1, (t+1)*32);
      asm volatile("s_waitcnt vmcnt(4)" ::: "memory");
    } else {
      asm volatile("s_waitcnt vmcnt(0)" ::: "memory");
    }
    __builtin_amdgcn_s_barrier();
    __builtin_amdgcn_sched_barrier(0);
    compute(cur);
    __builtin_amdgcn_s_barrier();
    cur ^= 1;
  }

  const int rowb = bm*128 + wr*64 + (lane>>4)*4;
  const int colb = bn*128 + wc*64 + (lane&15);
  const int Nst = nbn * 128;
  #pragma unroll
  for (int i=0;i<4;i++){
    #pragma unroll
    for (int j=0;j<4;j++){
      int col = colb + j*16;
      #pragma unroll
      for (int r=0;r<4;r++){
        int row = rowb + i*16 + r;
        if (row >= M) continue;
        float v = acc[i][j][r];
        if (EPI == 0){
          int bb = row / PP, p = row - bb*PP;
          Hout[((size_t)(bb*SS + 1 + p))*DD + col] = v + bias[col] + pos[p*DD + col];
        } else if (EPI == 1){
          Bout[(size_t)row*Nst + col] = f2bf(gelu_f(v + bias[col]));
        } else {
          Hout[(size_t)row*DD + col] += v + bias[col];
        }
      }
    }
  }
}

// ===== fc1 wide GEMM: 128x256 tile, per-wave 64x128 (acc[4][8]) =====
// Same round-13 sync skeleton (2-buffer, counted vmcnt(6) = loads/stage, two
// barriers/K-step) and same T2 chunk-XOR swizzle (rows still 64 B). LDS
// traffic per FLOP -25% vs 128x128 (12 b128 reads -> 32 MFMA vs 8 -> 16);
// barriers per FLOP halve. Direct test of the LDS-throughput-bound theory.
__global__ __launch_bounds__(256) void gemm_fc1_wide(
    const u16* __restrict__ A, const u16* __restrict__ BT, int M, int K,
    int nbm, int nbn,
    const float* __restrict__ bias, u16* __restrict__ Bout)
{
  __shared__ __align__(16) u16 As[2][128*32];
  __shared__ __align__(16) u16 Bs[2][256*32];
  const int tid = threadIdx.x;
  const int wave = tid>>6, lane = tid&63;

  const int nwg = nbm*nbn;
  const int wg = blockIdx.x;
  const int xcd = wg & 7, ii = wg >> 3;
  const int q8 = nwg >> 3, r8 = nwg & 7;
  const int lin = (xcd < r8 ? xcd*(q8+1) : r8*(q8+1) + (xcd-r8)*q8) + ii;
  const int bm = lin / nbn, bn = lin - bm*nbn;

  const int wr = wave>>1, wc = wave&1;

  f32x4 acc[4][8] = {};

  const int lr = lane>>2;
  const int lc = ((lane&3) ^ ((lane>>3)&3)) * 8;   // T2 permuted source chunk
  // A: wave stages rows [wave*32, wave*32+32) -> 2 gld16
  int ar0 = bm*128 + (wave*2+0)*16 + lr; if (ar0 > M-1) ar0 = M-1;
  int ar1 = bm*128 + (wave*2+1)*16 + lr; if (ar1 > M-1) ar1 = M-1;
  const u16* aS0 = A + (size_t)ar0*K + lc;
  const u16* aS1 = A + (size_t)ar1*K + lc;
  // B: wave stages rows [wave*64, wave*64+64) -> 4 gld16 (N=3072 exact, no clamp)
  const u16* bS[4];
  #pragma unroll
  for (int g=0; g<4; ++g)
    bS[g] = BT + (size_t)(bn*256 + wave*64 + g*16 + lr)*K + lc;
  const int da0 = (wave*2+0)*512, da1 = (wave*2+1)*512;

  auto stage = [&](int buf, int kt){
    gld16(aS0 + kt, &As[buf][da0]);
    gld16(aS1 + kt, &As[buf][da1]);
    #pragma unroll
    for (int g=0; g<4; ++g)
      gld16(bS[g] + kt, &Bs[buf][(wave*4+g)*512]);
  };
  const int rchunk = ((lane>>4) ^ (((lane&15)>>1)&3)) * 8;
  auto compute = [&](int buf){
    bf16x8 af[4], bfv[8];
    #pragma unroll
    for (int i=0;i<4;i++)
      af[i] = *reinterpret_cast<const bf16x8*>(&As[buf][(wr*64 + i*16 + (lane&15))*32 + rchunk]);
    #pragma unroll
    for (int j=0;j<8;j++)
      bfv[j] = *reinterpret_cast<const bf16x8*>(&Bs[buf][(wc*128 + j*16 + (lane&15))*32 + rchunk]);
    #pragma unroll
    for (int i=0;i<4;i++)
      #pragma unroll
      for (int j=0;j<8;j++)
        acc[i][j] = __builtin_amdgcn_mfma_f32_16x16x32_bf16(af[i], bfv[j], acc[i][j], 0, 0, 0);
  };

  const int NT = K >> 5;             // 24
  stage(0, 0);                       // 6 loads outstanding
  int cur = 0;
  for (int t = 0; t < NT; ++t){
    if (t+1 < NT){
      stage(cur^1, (t+1)*32);        // +6 loads
      asm volatile("s_waitcnt vmcnt(6)" ::: "memory");  // stage(t) retired
    } else {
      asm volatile("s_waitcnt vmcnt(0)" ::: "memory");
    }
    __builtin_amdgcn_s_barrier();
    __builtin_amdgcn_sched_barrier(0);
    compute(cur);
    __builtin_amdgcn_s_barrier();
    cur ^= 1;
  }

  const int rowb = bm*128 + wr*64 + (lane>>4)*4;
  const int colb = bn*256 + wc*128 + (lane&15);
  const int Nst = nbn * 256;         // 3072
  #pragma unroll
  for (int i=0;i<4;i++){
    #pragma unroll
    for (int j=0;j<8;j++){
      int col = colb + j*16;
      #pragma unroll
      for (int r=0;r<4;r++){
        int row = rowb + i*16 + r;
        if (row >= M) continue;
        Bout[(size_t)row*Nst + col] = f2bf(gelu_f(acc[i][j][r] + bias[col]));
      }
    }
  }
}

// ================= QKV with fused LN1: per-head batched MFMA =================
__global__ __launch_bounds__(256) void qkv_kernel(
    const float* __restrict__ h, const float2* __restrict__ stats,
    const float* __restrict__ lng, const float* __restrict__ lnb,
    const u16* __restrict__ WqT, const u16* __restrict__ WkT, const u16* __restrict__ WvT,
    const float* __restrict__ bq, const float* __restrict__ bk, const float* __restrict__ bv,
    u16* __restrict__ qb, u16* __restrict__ kb, u16* __restrict__ vb)
{
  const int LDA = 72;
  __shared__ __align__(16) u16 Asm[128*72];
  __shared__ __align__(16) u16 Wsm[3][64*72];
  const int tid = threadIdx.x, wave = tid>>6, lane = tid&63;
  const int bm = blockIdx.x, hd = blockIdx.y;

  {
    int row = tid>>1;                   // 0..127
    int col0 = (tid&1)*32;              // 0 or 32
    int gr = bm*128 + row; if (gr > NTOK-1) gr = NTOK-1;
    float2 st = stats[gr];
    const float4* src = reinterpret_cast<const float4*>(h + (size_t)gr*DD + hd*HDD + col0);
    const float* gg = lng + hd*HDD + col0;
    const float* bb = lnb + hd*HDD + col0;
    #pragma unroll
    for (int h4=0; h4<8; ++h4){
      float4 v = src[h4];
      u16x4 o = { f2bf((v.x-st.x)*st.y*gg[h4*4+0]+bb[h4*4+0]),
                  f2bf((v.y-st.x)*st.y*gg[h4*4+1]+bb[h4*4+1]),
                  f2bf((v.z-st.x)*st.y*gg[h4*4+2]+bb[h4*4+2]),
                  f2bf((v.w-st.x)*st.y*gg[h4*4+3]+bb[h4*4+3]) };
      *reinterpret_cast<u16x4*>(&Asm[row*LDA + col0 + h4*4]) = o;
    }
  }
  const u16* wsrc[3] = { WqT + hd*4096, WkT + hd*4096, WvT + hd*4096 };
  #pragma unroll
  for (int w=0; w<3; ++w)
    #pragma unroll
    for (int ps=0; ps<2; ++ps){
      int e = (ps*256 + tid)*8;
      int row = e>>6, col = e&63;
      *reinterpret_cast<int4*>(&Wsm[w][row*LDA + col]) =
          *reinterpret_cast<const int4*>(&wsrc[w][row*64 + col]);
    }
  __syncthreads();

  bf16x8 af[2][2];
  #pragma unroll
  for (int i=0;i<2;i++)
    #pragma unroll
    for (int kk=0;kk<2;kk++)
      af[i][kk] = *reinterpret_cast<const bf16x8*>(&Asm[(wave*32 + i*16 + (lane&15))*LDA + kk*32 + (lane>>4)*8]);

  f32x4 acc[3][2][4] = {};
  #pragma unroll
  for (int w=0;w<3;w++)
    #pragma unroll
    for (int kk=0;kk<2;kk++)
      #pragma unroll
      for (int j=0;j<4;j++){
        bf16x8 bfv = *reinterpret_cast<const bf16x8*>(&Wsm[w][(j*16 + (lane&15))*LDA + kk*32 + (lane>>4)*8]);
        #pragma unroll
        for (int i=0;i<2;i++)
          acc[w][i][j] = __builtin_amdgcn_mfma_f32_16x16x32_bf16(af[i][kk], bfv, acc[w][i][j], 0,0,0);
      }

  const float* bqh = bq + hd*HDD;
  const float* bkh = bk + hd*HDD;
  const float* bvh = bv + hd*HDD;
  #pragma unroll
  for (int i=0;i<2;i++)
    #pragma unroll
    for (int j=0;j<4;j++){
      int d = j*16 + (lane&15);
      #pragma unroll
      for (int r=0;r<4;r++){
        int t = bm*128 + wave*32 + i*16 + (lane>>4)*4 + r;
        if (t >= NTOK) continue;
        int b = t / SS, sx = t - b*SS;
        size_t bh = (size_t)b*HH + hd;
        qb[(bh*SS + sx)*HDD + d] = f2bf(acc[0][i][j][r] + bqh[d]);
        kb[(bh*SS + sx)*HDD + d] = f2bf(acc[1][i][j][r] + bkh[d]);
        vb[(bh*KPAD + sx)*HDD + d] = f2bf(acc[2][i][j][r] + bvh[d]);
      }
    }
}

// ========= fused scores+softmax: attn = softmax(q @ k^T / 8) bf16 =========
__global__ __launch_bounds__(256) void attn_scores_softmax_kernel(
    const u16* __restrict__ qb, const u16* __restrict__ kb, u16* __restrict__ attn)
{
  const int LDA = 72;
  __shared__ __align__(16) u16 Qs[128*72];
  __shared__ __align__(16) u16 Ks[KPAD*72];
  const int tid = threadIdx.x, wave = tid>>6, lane = tid&63;
  const int bm = blockIdx.x, bh = blockIdx.y;

  #pragma unroll
  for (int ps=0; ps<4; ++ps){
    int e = (ps*256 + tid)*8;
    int row = e>>6, col = e&63;
    int qr = bm*128 + row; if (qr > SS-1) qr = SS-1;
    *reinterpret_cast<int4*>(&Qs[row*LDA + col]) =
        *reinterpret_cast<const int4*>(&qb[((size_t)bh*SS + qr)*HDD + col]);
  }
  #pragma unroll
  for (int ps=0; ps<7; ++ps){
    int e = (ps*256 + tid)*8;
    int row = e>>6, col = e&63;
    int kr = row; if (kr > SS-1) kr = SS-1;
    *reinterpret_cast<int4*>(&Ks[row*LDA + col]) =
        *reinterpret_cast<const int4*>(&kb[((size_t)bh*SS + kr)*HDD + col]);
  }
  __syncthreads();

  bf16x8 af[2][2];
  #pragma unroll
  for (int i=0;i<2;i++)
    #pragma unroll
    for (int kk=0;kk<2;kk++)
      af[i][kk] = *reinterpret_cast<const bf16x8*>(&Qs[(wave*32 + i*16 + (lane&15))*LDA + kk*32 + (lane>>4)*8]);

  f32x4 acc[2][14];
  #pragma unroll
  for (int i=0;i<2;i++)
    #pragma unroll
    for (int j=0;j<14;j++)
      acc[i][j] = f32x4{0.f,0.f,0.f,0.f};

  #pragma unroll
  for (int kk=0;kk<2;kk++)
    #pragma unroll
    for (int j=0;j<14;j++){
      bf16x8 bfv = *reinterpret_cast<const bf16x8*>(&Ks[(j*16 + (lane&15))*LDA + kk*32 + (lane>>4)*8]);
      #pragma unroll
      for (int i=0;i<2;i++)
        acc[i][j] = __builtin_amdgcn_mfma_f32_16x16x32_bf16(af[i][kk], bfv, acc[i][j], 0,0,0);
    }

  const int kcol = lane & 15;
  #pragma unroll
  for (int i=0;i<2;i++){
    #pragma unroll
    for (int r=0;r<4;r++){
      int qg = bm*128 + wave*32 + i*16 + (lane>>4)*4 + r;
      float vals[14];
      float mx = -1e30f;
      #pragma unroll
      for (int j=0;j<14;j++){
        int kg = j*16 + kcol;
        float v = (kg < SS) ? acc[i][j][r]*0.125f : -1e30f;
        vals[j] = v;
        mx = fmaxf(mx, v);
      }
      mx = fmaxf(mx, __shfl_xor(mx,1)); mx = fmaxf(mx, __shfl_xor(mx,2));
      mx = fmaxf(mx, __shfl_xor(mx,4)); mx = fmaxf(mx, __shfl_xor(mx,8));
      float s = 0.f;
      #pragma unroll
      for (int j=0;j<14;j++){
        int kg = j*16 + kcol;
        float e = (kg < SS) ? expf(vals[j]-mx) : 0.f;
        vals[j] = e; s += e;
      }
      s += __shfl_xor(s,1); s += __shfl_xor(s,2);
      s += __shfl_xor(s,4); s += __shfl_xor(s,8);
      float inv = 1.f / s;
      if (qg < SS){
        u16* dst = attn + ((size_t)bh*SS + qg)*KPAD;
        #pragma unroll
        for (int j=0;j<14;j++)
          dst[j*16 + kcol] = f2bf(vals[j]*inv);   // pad cols get exact 0
      }
    }
  }
}

// mean over heads -> d_out attention maps
__global__ void attnmean_kernel(const u16* __restrict__ attn, float* __restrict__ outp){
  int qi = blockIdx.x, b = blockIdx.y, kk = threadIdx.x;
  if (kk >= SS) return;
  float s = 0.f;
  #pragma unroll
  for (int h=0; h<HH; ++h)
    s += bf2f(attn[(((size_t)b*HH + h)*SS + qi)*KPAD + kk]);
  outp[((size_t)b*SS + qi)*SS + kk] = s * (1.f/12.f);
}

// ================= o = attn @ v, h += o  (per b,h) =================
__global__ __launch_bounds__(256) void av_kernel(
    const u16* __restrict__ attn, const u16* __restrict__ vb, float* __restrict__ h)
{
  const int LDA = 40;
  const int LDB = 40;
  __shared__ __align__(16) u16 Asm[128*40];
  __shared__ __align__(16) u16 Bsm[64*40];
  const int tid = threadIdx.x, wave = tid>>6, lane = tid&63;
  const int bm = blockIdx.x, bh = blockIdx.y;
  const int b = bh / HH, hd = bh - b*HH;
  f32x4 acc[2][4] = {};
  for (int k0 = 0; k0 < KPAD; k0 += 32){
    if (k0) __syncthreads();
    #pragma unroll
    for (int ps=0; ps<2; ++ps){
      int e = (ps*256 + tid)*8;
      int row = e>>5, col = e&31;
      int ar = bm*128 + row; if (ar > SS-1) ar = SS-1;
      *reinterpret_cast<int4*>(&Asm[row*LDA + col]) =
          *reinterpret_cast<const int4*>(&attn[((size_t)bh*SS + ar)*KPAD + k0 + col]);
    }
    {
      int kk = tid>>3;
      int d0 = (tid&7)*8;
      bf16x8 vv = *reinterpret_cast<const bf16x8*>(&vb[((size_t)bh*KPAD + k0 + kk)*HDD + d0]);
      #pragma unroll
      for (int q=0;q<8;q++) Bsm[(d0+q)*LDB + kk] = (u16)vv[q];
    }
    __syncthreads();
    bf16x8 af[2], bfv[4];
    #pragma unroll
    for (int i=0;i<2;i++) af[i] = *reinterpret_cast<const bf16x8*>(&Asm[(wave*32 + i*16 + (lane&15))*LDA + (lane>>4)*8]);
    #pragma unroll
    for (int j=0;j<4;j++) bfv[j] = *reinterpret_cast<const bf16x8*>(&Bsm[(j*16 + (lane&15))*LDB + (lane>>4)*8]);
    #pragma unroll
    for (int i=0;i<2;i++)
      #pragma unroll
      for (int j=0;j<4;j++)
        acc[i][j] = __builtin_amdgcn_mfma_f32_16x16x32_bf16(af[i], bfv[j], acc[i][j], 0,0,0);
  }
  #pragma unroll
  for (int i=0;i<2;i++)
    #pragma unroll
    for (int j=0;j<4;j++){
      int d = j*16 + (lane&15);
      #pragma unroll
      for (int r=0;r<4;r++){
        int sx = bm*128 + wave*32 + i*16 + (lane>>4)*4 + r;
        if (sx < SS)
          h[((size_t)b*SS + sx)*DD + hd*HDD + d] += acc[i][j][r];
      }
    }
}

// ================= classifier: logits (parallel over class chunks) =================
__global__ __launch_bounds__(256) void logits_kernel(
    const float* __restrict__ h, const float* __restrict__ Wc,
    const float* __restrict__ bc, float* __restrict__ logits)
{
  __shared__ float xs[DD];
  const int b = blockIdx.x, tid = threadIdx.x;
  for (int i = tid; i < DD; i += 256) xs[i] = h[(size_t)b*SS*DD + i];
  __syncthreads();
  const int c = blockIdx.y*250 + tid;
  if (tid >= 250 || c >= NCLS) return;
  float acc = bc[c];
  const float* wcol = Wc + c;
  #pragma unroll 16
  for (int k = 0; k < DD; ++k)
    acc += xs[k] * wcol[(size_t)k*NCLS];
  logits[(size_t)b*NCLS + c] = acc;
}

// softmax over 1000 logits, one block per batch row
__global__ __launch_bounds__(256) void pred_softmax_kernel(
    const float* __restrict__ logits, float* __restrict__ outp)
{
  __shared__ float red[256];
  const int b = blockIdx.x, tid = threadIdx.x;
  float acc[4], mx = -1e30f;
  #pragma unroll
  for (int m=0;m<4;m++){
    int c = tid + m*256;
    acc[m] = (c < NCLS) ? logits[(size_t)b*NCLS + c] : -1e30f;
    mx = fmaxf(mx, acc[m]);
  }
  red[tid] = mx; __syncthreads();
  for (int o=128;o>0;o>>=1){ if (tid<o) red[tid] = fmaxf(red[tid], red[tid+o]); __syncthreads(); }
  mx = red[0]; __syncthreads();
  float ex[4]; float s = 0.f;
  #pragma unroll
  for (int m=0;m<4;m++){
    int c = tid + m*256;
    ex[m] = (c < NCLS) ? expf(acc[m]-mx) : 0.f;
    s += ex[m];
  }
  red[tid] = s; __syncthreads();
  for (int o=128;o>0;o>>=1){ if (tid<o) red[tid] += red[tid+o]; __syncthreads(); }
  float inv = 1.f / red[0];
  #pragma unroll
  for (int m=0;m<4;m++){
    int c = tid + m*256;
    if (c < NCLS) outp[(size_t)b*NCLS + c] = ex[m]*inv;
  }
}

// ================= host =================
extern "C" void kernel_launch(void* const* d_in, const int* in_sizes, int n_in,
                              void* d_out, int out_size, void* d_ws, size_t ws_size,
                              hipStream_t stream)
{
  const float* x      = (const float*)d_in[0];
  const float* W_emb  = (const float*)d_in[1];
  const float* b_emb  = (const float*)d_in[2];
  const float* v_class= (const float*)d_in[3];
  const float* ln1_g  = (const float*)d_in[4];
  const float* ln1_b  = (const float*)d_in[5];
  const float* Wq     = (const float*)d_in[6];
  const float* bq     = (const float*)d_in[7];
  const float* Wk     = (const float*)d_in[8];
  const float* bk     = (const float*)d_in[9];
  const float* Wv     = (const float*)d_in[10];
  const float* bv     = (const float*)d_in[11];
  const float* ln2_g  = (const float*)d_in[12];
  const float* ln2_b  = (const float*)d_in[13];
  const float* W1     = (const float*)d_in[14];
  const float* b1     = (const float*)d_in[15];
  const float* W2     = (const float*)d_in[16];
  const float* b2     = (const float*)d_in[17];
  const float* W_cls  = (const float*)d_in[18];
  const float* b_cls  = (const float*)d_in[19];
  (void)in_sizes; (void)n_in; (void)out_size;
  float* outp = (float*)d_out;

  char* ws = (char*)d_ws;
  size_t off = 0;
  auto alloc = [&](size_t bytes)->char*{
    char* p = ws + off;
    off = (off + bytes + 255) & ~((size_t)255);
    return p;
  };
  float* pos    = (float*)alloc((size_t)PP*DD*4);
  float* hbuf   = (float*)alloc((size_t)NTOK*DD*4);
  u16*   xnb    = (u16*)  alloc((size_t)NTOK*DD*2);
  float2* statsb= (float2*)alloc((size_t)NTOK*8);
  u16*   WembT  = (u16*)  alloc((size_t)DD*DD*2);
  u16*   W1Tall = (u16*)  alloc((size_t)NLAY*DD*DD4*2);
  u16*   W2Tall = (u16*)  alloc((size_t)NLAY*DD*DD4*2);
  u16*   WqT    = (u16*)  alloc((size_t)NLAY*HH*HDD*HDD*2);
  u16*   WkT    = (u16*)  alloc((size_t)NLAY*HH*HDD*HDD*2);
  u16*   WvT    = (u16*)  alloc((size_t)NLAY*HH*HDD*HDD*2);
  // blob: holds q/k/v/attn during attention phase, then fc1's m during MLP
  char*  blob   = alloc((size_t)NTOK*DD4*2);   // 38.7 MB (mbuf size, superset)
  float* logitsb= (float*)alloc((size_t)BB*NCLS*4);
  u16* qbuf = (u16*)blob;
  u16* kbuf = qbuf + (size_t)NBH*SS*HDD;
  u16* vbuf = kbuf + (size_t)NBH*SS*HDD;
  u16* scb  = vbuf + (size_t)NBH*KPAD*HDD;     // attn (bf16); ends ~32.7MB into blob
  u16* mbuf = (u16*)blob;                      // fc1 out, 38.7MB (q/k/v/attn dead by then)
  u16* xbf  = scb;                             // x bf16 (9.2MB); dead before layer-0 attn
  if (ws_size < off) return;    // all-zero output signals ws too small

  hipMemsetAsync(vbuf, 0, (size_t)NBH*KPAD*HDD*2, stream);  // NaN-proof pad rows
  pos_kernel<<<(PP*DD+255)/256, 256, 0, stream>>>(pos);
  f32_to_bf16_kernel<<<(NTOKX*DD/4+255)/256, 256, 0, stream>>>(x, xbf, NTOKX*DD/4);
  dim3 tb(32,8);
  transpose_kernel<<<dim3(DD/32, DD/32, 1), tb, 0, stream>>>(W_emb, WembT, DD, DD);
  transpose_kernel<<<dim3(2,2,NLAY*HH), tb, 0, stream>>>(Wq, WqT, HDD, HDD);
  transpose_kernel<<<dim3(2,2,NLAY*HH), tb, 0, stream>>>(Wk, WkT, HDD, HDD);
  transpose_kernel<<<dim3(2,2,NLAY*HH), tb, 0, stream>>>(Wv, WvT, HDD, HDD);
  // all-layer weight transposes hoisted out of the loop (z = layer)
  transpose_kernel<<<dim3(DD4/32, DD/32, NLAY), tb, 0, stream>>>(W1, W1Tall, DD, DD4);
  transpose_kernel<<<dim3(DD/32, DD4/32, NLAY), tb, 0, stream>>>(W2, W2Tall, DD4, DD);

  gemm_bf16<0><<<49*6, 256, 0, stream>>>(xbf, WembT, NTOKX, DD, 49, 6, b_emb, pos, hbuf, nullptr);
  clstok_kernel<<<BB, 256, 0, stream>>>(v_class, hbuf);

  for (int l=0; l<NLAY; ++l){
    ln_stats_kernel<<<NTOK/4, 256, 0, stream>>>(hbuf, statsb);
    qkv_kernel<<<dim3(50, HH), 256, 0, stream>>>(hbuf, statsb,
        ln1_g + l*DD, ln1_b + l*DD,
        WqT + (size_t)l*HH*4096, WkT + (size_t)l*HH*4096, WvT + (size_t)l*HH*4096,
        bq + l*HH*HDD, bk + l*HH*HDD, bv + l*HH*HDD, qbuf, kbuf, vbuf);
    attn_scores_softmax_kernel<<<dim3(2, NBH), 256, 0, stream>>>(qbuf, kbuf, scb);
    attnmean_kernel<<<dim3(SS, BB), 256, 0, stream>>>(scb, outp + 32000 + (size_t)l*BB*SS*SS);
    av_kernel<<<dim3(2, NBH), 256, 0, stream>>>(scb, vbuf, hbuf);
    ln_kernel<<<NTOK/4, 256, 0, stream>>>(hbuf, ln2_g + l*DD, ln2_b + l*DD, xnb);
    gemm_fc1_wide<<<50*12, 256, 0, stream>>>(xnb, W1Tall + (size_t)l*DD*DD4, NTOK, DD, 50, 12,
                                             b1 + l*DD4, mbuf);
    gemm_bf16<2><<<50*6, 256, 0, stream>>>(mbuf, W2Tall + (size_t)l*DD*DD4, NTOK, DD4, 50, 6,
                                           b2 + l*DD, nullptr, hbuf, nullptr);
  }
  logits_kernel<<<dim3(BB, 4), 256, 0, stream>>>(hbuf, W_cls, b_cls, logitsb);
  pred_softmax_kernel<<<BB, 256, 0, stream>>>(logitsb, outp);
}

// Round 18
// 1851.350 us; speedup vs baseline: 1.2687x; 1.2687x over previous
//
#include <hip/hip_runtime.h>
#include <cstdint>

typedef unsigned short u16;
typedef __attribute__((ext_vector_type(8))) short bf16x8;
typedef __attribute__((ext_vector_type(4))) float f32x4;

#define DEV static __device__ __forceinline__

// ---- problem dims ----
#define BB 32
#define PP 196
#define DD 768
#define HH 12
#define HDD 64
#define SS 197
#define NTOK 6304    // 32*197
#define NTOKX 6272   // 32*196
#define NCLS 1000
#define DD4 3072
#define KPAD 224     // padded attention K (197 -> 224 = 7*32)
#define NBH 384      // 32*12
#define NLAY 8

DEV u16 f2bf(float f){ unsigned u=__float_as_uint(f); u += 0x7FFFu + ((u>>16)&1u); return (u16)(u>>16); }
DEV float bf2f(u16 u){ return __uint_as_float(((unsigned)u)<<16); }

// gelu via A&S 7.1.26 erf poly (|err| <= 1.5e-7, below bf16 rounding).
DEV float gelu_f(float x){
  float z  = 0.70710678118654752f * x;
  float az = fabsf(z);
  float t  = __builtin_amdgcn_rcpf(fmaf(0.3275911f, az, 1.f));
  float poly = t*(0.254829592f + t*(-0.284496736f + t*(1.421413741f + t*(-1.453152027f + t*1.061405429f))));
  float e  = __expf(-az*az);
  float erf_abs = 1.f - poly*e;
  float erfv = copysignf(erf_abs, x);
  return 0.5f * x * (1.f + erfv);
}

typedef __attribute__((address_space(1))) void gas1;
typedef __attribute__((address_space(3))) void las3;

DEV void gld16(const void* g, void* l){
  __builtin_amdgcn_global_load_lds((gas1*)(uintptr_t)g, (las3*)(unsigned)(uintptr_t)l, 16, 0, 0);
}

struct __align__(8) u16x4 { u16 x,y,z,w; };

// ================= small kernels =================

// Reference parity is on the POSITION index (rows), not the feature index.
__global__ void pos_kernel(float* __restrict__ pos){
  int idx = blockIdx.x*256 + threadIdx.x;
  if (idx >= PP*DD) return;
  int p = idx / DD, j = idx - p*DD;
  int odd = p & 1;
  float e = ((float)j - (float)odd) * (1.0f/(float)DD);
  float arg = (float)p / powf(10000.0f, e);
  pos[idx] = odd ? cosf(arg) : sinf(arg);
}

__global__ void f32_to_bf16_kernel(const float* __restrict__ in, u16* __restrict__ out, int n4){
  int i = blockIdx.x*256 + threadIdx.x;
  if (i >= n4) return;
  float4 v = reinterpret_cast<const float4*>(in)[i];
  u16x4 o = { f2bf(v.x), f2bf(v.y), f2bf(v.z), f2bf(v.w) };
  reinterpret_cast<u16x4*>(out)[i] = o;
}

__global__ void clstok_kernel(const float* __restrict__ vcls, float* __restrict__ h){
  int b = blockIdx.x;
  for (int i = threadIdx.x; i < DD; i += 256)
    h[(size_t)b*SS*DD + i] = vcls[i];
}

// transpose f32 (R x C) -> bf16 (C x R), batched over blockIdx.z. block (32,8)
__global__ void transpose_kernel(const float* __restrict__ in, u16* __restrict__ out, int R, int C){
  __shared__ float tile[32][33];
  int bx = blockIdx.x*32, by = blockIdx.y*32;
  size_t zoff = (size_t)blockIdx.z * R * C;
  const float* src = in + zoff;
  u16* dst = out + zoff;
  int tx = threadIdx.x, ty = threadIdx.y;
  #pragma unroll
  for (int q=0;q<4;q++)
    tile[ty + q*8][tx] = src[(size_t)(by + ty + q*8)*C + bx + tx];
  __syncthreads();
  #pragma unroll
  for (int q=0;q<4;q++)
    dst[(size_t)(bx + ty + q*8)*R + by + tx] = f2bf(tile[tx][ty + q*8]);
}

// LN stats only: one wave per token -> (mean, rstd)
__global__ void ln_stats_kernel(const float* __restrict__ h, float2* __restrict__ stats){
  int t = blockIdx.x*4 + (threadIdx.x>>6);
  int lane = threadIdx.x & 63;
  const float4* src = reinterpret_cast<const float4*>(h + (size_t)t*DD);
  float s = 0.f, s2 = 0.f;
  #pragma unroll
  for (int p=0;p<3;p++){
    float4 v = src[p*64 + lane];
    s  += v.x + v.y + v.z + v.w;
    s2 += v.x*v.x + v.y*v.y + v.z*v.z + v.w*v.w;
  }
  #pragma unroll
  for (int o=32;o>0;o>>=1){ s += __shfl_xor(s,o); s2 += __shfl_xor(s2,o); }
  if (lane == 0){
    float mean = s * (1.f/(float)DD);
    float rstd = rsqrtf(s2*(1.f/(float)DD) - mean*mean + 1e-5f);
    stats[t] = make_float2(mean, rstd);
  }
}

// LayerNorm: one wave per token. h f32 -> xn bf16 (used for ln2 -> fc1 input)
__global__ void ln_kernel(const float* __restrict__ h, const float* __restrict__ g,
                          const float* __restrict__ b, u16* __restrict__ xn){
  int t = blockIdx.x*4 + (threadIdx.x>>6);
  int lane = threadIdx.x & 63;
  const float4* src = reinterpret_cast<const float4*>(h + (size_t)t*DD);
  float4 xv[3];
  float s = 0.f, s2 = 0.f;
  #pragma unroll
  for (int p=0;p<3;p++){
    xv[p] = src[p*64 + lane];
    s  += xv[p].x + xv[p].y + xv[p].z + xv[p].w;
    s2 += xv[p].x*xv[p].x + xv[p].y*xv[p].y + xv[p].z*xv[p].z + xv[p].w*xv[p].w;
  }
  #pragma unroll
  for (int o=32;o>0;o>>=1){ s += __shfl_xor(s,o); s2 += __shfl_xor(s2,o); }
  float mean = s * (1.f/(float)DD);
  float rstd = rsqrtf(s2*(1.f/(float)DD) - mean*mean + 1e-5f);
  #pragma unroll
  for (int p=0;p<3;p++){
    int base = p*256 + lane*4;
    u16x4 o4 = { f2bf((xv[p].x-mean)*rstd*g[base+0]+b[base+0]),
                 f2bf((xv[p].y-mean)*rstd*g[base+1]+b[base+1]),
                 f2bf((xv[p].z-mean)*rstd*g[base+2]+b[base+2]),
                 f2bf((xv[p].w-mean)*rstd*g[base+3]+b[base+3]) };
    *reinterpret_cast<u16x4*>(&xn[(size_t)t*DD + base]) = o4;
  }
}

// ===== main 128x128 bf16 GEMM (round-13 proven config: 68 us) =====
// T1 XCD-swizzled grid + T2 chunk-XOR LDS swizzle + 2-buffer counted-vmcnt
// prefetch (32 KB LDS). BK=32.
// EPI 0: h[b,1+p,:] = acc + bias + pos   (emb)
// EPI 1: m = bf16(gelu(acc + bias))      (mlp fc1)
// EPI 2: h[row,:] += acc + bias          (mlp fc2 residual)
template<int EPI>
__global__ __launch_bounds__(256) void gemm_bf16(
    const u16* __restrict__ A, const u16* __restrict__ BT, int M, int K,
    int nbm, int nbn,
    const float* __restrict__ bias, const float* __restrict__ pos,
    float* __restrict__ Hout, u16* __restrict__ Bout)
{
  __shared__ __align__(16) u16 As[2][128*32];
  __shared__ __align__(16) u16 Bs[2][128*32];
  const int tid = threadIdx.x;
  const int wave = tid>>6, lane = tid&63;

  // XCD-bijective chunk swizzle (m204): XCD x owns a contiguous logical range.
  const int nwg = nbm*nbn;
  const int wg = blockIdx.x;
  const int xcd = wg & 7, ii = wg >> 3;
  const int q8 = nwg >> 3, r8 = nwg & 7;
  const int lin = (xcd < r8 ? xcd*(q8+1) : r8*(q8+1) + (xcd-r8)*q8) + ii;
  const int bm = lin / nbn, bn = lin - bm*nbn;

  const int wr = wave>>1, wc = wave&1;

  f32x4 acc[4][4] = {};

  // Staging: wave w loads A-chunks 2w,2w+1 and B-chunks 2w,2w+1 (16 rows each).
  // T2 swizzle: source 16B-chunk permuted, gld16 dest LINEAR (rule #21).
  const int lr = lane>>2;
  const int lc = ((lane&3) ^ ((lane>>3)&3)) * 8;   // permuted source chunk
  int ar0 = bm*128 + (wave*2+0)*16 + lr; if (ar0 > M-1) ar0 = M-1;
  int ar1 = bm*128 + (wave*2+1)*16 + lr; if (ar1 > M-1) ar1 = M-1;
  const u16* aS0 = A + (size_t)ar0*K + lc;
  const u16* aS1 = A + (size_t)ar1*K + lc;
  const u16* bS0 = BT + (size_t)(bn*128 + (wave*2+0)*16 + lr)*K + lc;
  const u16* bS1 = BT + (size_t)(bn*128 + (wave*2+1)*16 + lr)*K + lc;
  const int d0 = (wave*2+0)*512;
  const int d1 = (wave*2+1)*512;

  auto stage = [&](int buf, int kt){
    gld16(aS0 + kt, &As[buf][d0]);
    gld16(aS1 + kt, &As[buf][d1]);
    gld16(bS0 + kt, &Bs[buf][d0]);
    gld16(bS1 + kt, &Bs[buf][d1]);
  };
  // Read un-permutes: chunk = (lane>>4) ^ ((row>>1)&3); row low bits = lane&15.
  const int rchunk = ((lane>>4) ^ (((lane&15)>>1)&3)) * 8;
  auto compute = [&](int buf){
    bf16x8 af[4], bfv[4];
    #pragma unroll
    for (int i=0;i<4;i++)
      af[i] = *reinterpret_cast<const bf16x8*>(&As[buf][(wr*64 + i*16 + (lane&15))*32 + rchunk]);
    #pragma unroll
    for (int j=0;j<4;j++)
      bfv[j] = *reinterpret_cast<const bf16x8*>(&Bs[buf][(wc*64 + j*16 + (lane&15))*32 + rchunk]);
    #pragma unroll
    for (int i=0;i<4;i++)
      #pragma unroll
      for (int j=0;j<4;j++)
        acc[i][j] = __builtin_amdgcn_mfma_f32_16x16x32_bf16(af[i], bfv[j], acc[i][j], 0, 0, 0);
  };

  const int NT = K >> 5;
  stage(0, 0);                       // prologue: 4 loads outstanding
  int cur = 0;
  for (int t = 0; t < NT; ++t){
    if (t+1 < NT){
      stage(cur^1, (t+1)*32);        // buf^1 free (consumed in t-1, barrier passed)
      asm volatile("s_waitcnt vmcnt(4)" ::: "memory");  // stage(t) retired, t+1 in flight
    } else {
      asm volatile("s_waitcnt vmcnt(0)" ::: "memory");
    }
    __builtin_amdgcn_s_barrier();    // all waves: tile t in LDS
    __builtin_amdgcn_sched_barrier(0);
    compute(cur);
    __builtin_amdgcn_s_barrier();    // all waves done reading cur before overwrite
    cur ^= 1;
  }

  const int rowb = bm*128 + wr*64 + (lane>>4)*4;
  const int colb = bn*128 + wc*64 + (lane&15);
  const int Nst = nbn * 128;
  #pragma unroll
  for (int i=0;i<4;i++){
    #pragma unroll
    for (int j=0;j<4;j++){
      int col = colb + j*16;
      #pragma unroll
      for (int r=0;r<4;r++){
        int row = rowb + i*16 + r;
        if (row >= M) continue;
        float v = acc[i][j][r];
        if (EPI == 0){
          int bb = row / PP, p = row - bb*PP;
          Hout[((size_t)(bb*SS + 1 + p))*DD + col] = v + bias[col] + pos[p*DD + col];
        } else if (EPI == 1){
          Bout[(size_t)row*Nst + col] = f2bf(gelu_f(v + bias[col]));
        } else {
          Hout[(size_t)row*DD + col] += v + bias[col];
        }
      }
    }
  }
}

// ================= QKV with fused LN1: per-head batched MFMA =================
__global__ __launch_bounds__(256) void qkv_kernel(
    const float* __restrict__ h, const float2* __restrict__ stats,
    const float* __restrict__ lng, const float* __restrict__ lnb,
    const u16* __restrict__ WqT, const u16* __restrict__ WkT, const u16* __restrict__ WvT,
    const float* __restrict__ bq, const float* __restrict__ bk, const float* __restrict__ bv,
    u16* __restrict__ qb, u16* __restrict__ kb, u16* __restrict__ vb)
{
  const int LDA = 72;
  __shared__ __align__(16) u16 Asm[128*72];
  __shared__ __align__(16) u16 Wsm[3][64*72];
  const int tid = threadIdx.x, wave = tid>>6, lane = tid&63;
  const int bm = blockIdx.x, hd = blockIdx.y;

  {
    int row = tid>>1;                   // 0..127
    int col0 = (tid&1)*32;              // 0 or 32
    int gr = bm*128 + row; if (gr > NTOK-1) gr = NTOK-1;
    float2 st = stats[gr];
    const float4* src = reinterpret_cast<const float4*>(h + (size_t)gr*DD + hd*HDD + col0);
    const float* gg = lng + hd*HDD + col0;
    const float* bb = lnb + hd*HDD + col0;
    #pragma unroll
    for (int h4=0; h4<8; ++h4){
      float4 v = src[h4];
      u16x4 o = { f2bf((v.x-st.x)*st.y*gg[h4*4+0]+bb[h4*4+0]),
                  f2bf((v.y-st.x)*st.y*gg[h4*4+1]+bb[h4*4+1]),
                  f2bf((v.z-st.x)*st.y*gg[h4*4+2]+bb[h4*4+2]),
                  f2bf((v.w-st.x)*st.y*gg[h4*4+3]+bb[h4*4+3]) };
      *reinterpret_cast<u16x4*>(&Asm[row*LDA + col0 + h4*4]) = o;
    }
  }
  const u16* wsrc[3] = { WqT + hd*4096, WkT + hd*4096, WvT + hd*4096 };
  #pragma unroll
  for (int w=0; w<3; ++w)
    #pragma unroll
    for (int ps=0; ps<2; ++ps){
      int e = (ps*256 + tid)*8;
      int row = e>>6, col = e&63;
      *reinterpret_cast<int4*>(&Wsm[w][row*LDA + col]) =
          *reinterpret_cast<const int4*>(&wsrc[w][row*64 + col]);
    }
  __syncthreads();

  bf16x8 af[2][2];
  #pragma unroll
  for (int i=0;i<2;i++)
    #pragma unroll
    for (int kk=0;kk<2;kk++)
      af[i][kk] = *reinterpret_cast<const bf16x8*>(&Asm[(wave*32 + i*16 + (lane&15))*LDA + kk*32 + (lane>>4)*8]);

  f32x4 acc[3][2][4] = {};
  #pragma unroll
  for (int w=0;w<3;w++)
    #pragma unroll
    for (int kk=0;kk<2;kk++)
      #pragma unroll
      for (int j=0;j<4;j++){
        bf16x8 bfv = *reinterpret_cast<const bf16x8*>(&Wsm[w][(j*16 + (lane&15))*LDA + kk*32 + (lane>>4)*8]);
        #pragma unroll
        for (int i=0;i<2;i++)
          acc[w][i][j] = __builtin_amdgcn_mfma_f32_16x16x32_bf16(af[i][kk], bfv, acc[w][i][j], 0,0,0);
      }

  const float* bqh = bq + hd*HDD;
  const float* bkh = bk + hd*HDD;
  const float* bvh = bv + hd*HDD;
  #pragma unroll
  for (int i=0;i<2;i++)
    #pragma unroll
    for (int j=0;j<4;j++){
      int d = j*16 + (lane&15);
      #pragma unroll
      for (int r=0;r<4;r++){
        int t = bm*128 + wave*32 + i*16 + (lane>>4)*4 + r;
        if (t >= NTOK) continue;
        int b = t / SS, sx = t - b*SS;
        size_t bh = (size_t)b*HH + hd;
        qb[(bh*SS + sx)*HDD + d] = f2bf(acc[0][i][j][r] + bqh[d]);
        kb[(bh*SS + sx)*HDD + d] = f2bf(acc[1][i][j][r] + bkh[d]);
        vb[(bh*KPAD + sx)*HDD + d] = f2bf(acc[2][i][j][r] + bvh[d]);
      }
    }
}

// ========= fused scores+softmax: attn = softmax(q @ k^T / 8) bf16 =========
__global__ __launch_bounds__(256) void attn_scores_softmax_kernel(
    const u16* __restrict__ qb, const u16* __restrict__ kb, u16* __restrict__ attn)
{
  const int LDA = 72;
  __shared__ __align__(16) u16 Qs[128*72];
  __shared__ __align__(16) u16 Ks[KPAD*72];
  const int tid = threadIdx.x, wave = tid>>6, lane = tid&63;
  const int bm = blockIdx.x, bh = blockIdx.y;

  #pragma unroll
  for (int ps=0; ps<4; ++ps){
    int e = (ps*256 + tid)*8;
    int row = e>>6, col = e&63;
    int qr = bm*128 + row; if (qr > SS-1) qr = SS-1;
    *reinterpret_cast<int4*>(&Qs[row*LDA + col]) =
        *reinterpret_cast<const int4*>(&qb[((size_t)bh*SS + qr)*HDD + col]);
  }
  #pragma unroll
  for (int ps=0; ps<7; ++ps){
    int e = (ps*256 + tid)*8;
    int row = e>>6, col = e&63;
    int kr = row; if (kr > SS-1) kr = SS-1;
    *reinterpret_cast<int4*>(&Ks[row*LDA + col]) =
        *reinterpret_cast<const int4*>(&kb[((size_t)bh*SS + kr)*HDD + col]);
  }
  __syncthreads();

  bf16x8 af[2][2];
  #pragma unroll
  for (int i=0;i<2;i++)
    #pragma unroll
    for (int kk=0;kk<2;kk++)
      af[i][kk] = *reinterpret_cast<const bf16x8*>(&Qs[(wave*32 + i*16 + (lane&15))*LDA + kk*32 + (lane>>4)*8]);

  f32x4 acc[2][14];
  #pragma unroll
  for (int i=0;i<2;i++)
    #pragma unroll
    for (int j=0;j<14;j++)
      acc[i][j] = f32x4{0.f,0.f,0.f,0.f};

  #pragma unroll
  for (int kk=0;kk<2;kk++)
    #pragma unroll
    for (int j=0;j<14;j++){
      bf16x8 bfv = *reinterpret_cast<const bf16x8*>(&Ks[(j*16 + (lane&15))*LDA + kk*32 + (lane>>4)*8]);
      #pragma unroll
      for (int i=0;i<2;i++)
        acc[i][j] = __builtin_amdgcn_mfma_f32_16x16x32_bf16(af[i][kk], bfv, acc[i][j], 0,0,0);
    }

  const int kcol = lane & 15;
  #pragma unroll
  for (int i=0;i<2;i++){
    #pragma unroll
    for (int r=0;r<4;r++){
      int qg = bm*128 + wave*32 + i*16 + (lane>>4)*4 + r;
      float vals[14];
      float mx = -1e30f;
      #pragma unroll
      for (int j=0;j<14;j++){
        int kg = j*16 + kcol;
        float v = (kg < SS) ? acc[i][j][r]*0.125f : -1e30f;
        vals[j] = v;
        mx = fmaxf(mx, v);
      }
      mx = fmaxf(mx, __shfl_xor(mx,1)); mx = fmaxf(mx, __shfl_xor(mx,2));
      mx = fmaxf(mx, __shfl_xor(mx,4)); mx = fmaxf(mx, __shfl_xor(mx,8));
      float s = 0.f;
      #pragma unroll
      for (int j=0;j<14;j++){
        int kg = j*16 + kcol;
        float e = (kg < SS) ? expf(vals[j]-mx) : 0.f;
        vals[j] = e; s += e;
      }
      s += __shfl_xor(s,1); s += __shfl_xor(s,2);
      s += __shfl_xor(s,4); s += __shfl_xor(s,8);
      float inv = 1.f / s;
      if (qg < SS){
        u16* dst = attn + ((size_t)bh*SS + qg)*KPAD;
        #pragma unroll
        for (int j=0;j<14;j++)
          dst[j*16 + kcol] = f2bf(vals[j]*inv);   // pad cols get exact 0
      }
    }
  }
}

// mean over heads -> d_out attention maps
__global__ void attnmean_kernel(const u16* __restrict__ attn, float* __restrict__ outp){
  int qi = blockIdx.x, b = blockIdx.y, kk = threadIdx.x;
  if (kk >= SS) return;
  float s = 0.f;
  #pragma unroll
  for (int h=0; h<HH; ++h)
    s += bf2f(attn[(((size_t)b*HH + h)*SS + qi)*KPAD + kk]);
  outp[((size_t)b*SS + qi)*SS + kk] = s * (1.f/12.f);
}

// ================= o = attn @ v, h += o  (per b,h) =================
__global__ __launch_bounds__(256) void av_kernel(
    const u16* __restrict__ attn, const u16* __restrict__ vb, float* __restrict__ h)
{
  const int LDA = 40;
  const int LDB = 40;
  __shared__ __align__(16) u16 Asm[128*40];
  __shared__ __align__(16) u16 Bsm[64*40];
  const int tid = threadIdx.x, wave = tid>>6, lane = tid&63;
  const int bm = blockIdx.x, bh = blockIdx.y;
  const int b = bh / HH, hd = bh - b*HH;
  f32x4 acc[2][4] = {};
  for (int k0 = 0; k0 < KPAD; k0 += 32){
    if (k0) __syncthreads();
    #pragma unroll
    for (int ps=0; ps<2; ++ps){
      int e = (ps*256 + tid)*8;
      int row = e>>5, col = e&31;
      int ar = bm*128 + row; if (ar > SS-1) ar = SS-1;
      *reinterpret_cast<int4*>(&Asm[row*LDA + col]) =
          *reinterpret_cast<const int4*>(&attn[((size_t)bh*SS + ar)*KPAD + k0 + col]);
    }
    {
      int kk = tid>>3;
      int d0 = (tid&7)*8;
      bf16x8 vv = *reinterpret_cast<const bf16x8*>(&vb[((size_t)bh*KPAD + k0 + kk)*HDD + d0]);
      #pragma unroll
      for (int q=0;q<8;q++) Bsm[(d0+q)*LDB + kk] = (u16)vv[q];
    }
    __syncthreads();
    bf16x8 af[2], bfv[4];
    #pragma unroll
    for (int i=0;i<2;i++) af[i] = *reinterpret_cast<const bf16x8*>(&Asm[(wave*32 + i*16 + (lane&15))*LDA + (lane>>4)*8]);
    #pragma unroll
    for (int j=0;j<4;j++) bfv[j] = *reinterpret_cast<const bf16x8*>(&Bsm[(j*16 + (lane&15))*LDB + (lane>>4)*8]);
    #pragma unroll
    for (int i=0;i<2;i++)
      #pragma unroll
      for (int j=0;j<4;j++)
        acc[i][j] = __builtin_amdgcn_mfma_f32_16x16x32_bf16(af[i], bfv[j], acc[i][j], 0,0,0);
  }
  #pragma unroll
  for (int i=0;i<2;i++)
    #pragma unroll
    for (int j=0;j<4;j++){
      int d = j*16 + (lane&15);
      #pragma unroll
      for (int r=0;r<4;r++){
        int sx = bm*128 + wave*32 + i*16 + (lane>>4)*4 + r;
        if (sx < SS)
          h[((size_t)b*SS + sx)*DD + hd*HDD + d] += acc[i][j][r];
      }
    }
}

// ================= classifier: logits (parallel over class chunks) =================
__global__ __launch_bounds__(256) void logits_kernel(
    const float* __restrict__ h, const float* __restrict__ Wc,
    const float* __restrict__ bc, float* __restrict__ logits)
{
  __shared__ float xs[DD];
  const int b = blockIdx.x, tid = threadIdx.x;
  for (int i = tid; i < DD; i += 256) xs[i] = h[(size_t)b*SS*DD + i];
  __syncthreads();
  const int c = blockIdx.y*250 + tid;
  if (tid >= 250 || c >= NCLS) return;
  float acc = bc[c];
  const float* wcol = Wc + c;
  #pragma unroll 16
  for (int k = 0; k < DD; ++k)
    acc += xs[k] * wcol[(size_t)k*NCLS];
  logits[(size_t)b*NCLS + c] = acc;
}

// softmax over 1000 logits, one block per batch row
__global__ __launch_bounds__(256) void pred_softmax_kernel(
    const float* __restrict__ logits, float* __restrict__ outp)
{
  __shared__ float red[256];
  const int b = blockIdx.x, tid = threadIdx.x;
  float acc[4], mx = -1e30f;
  #pragma unroll
  for (int m=0;m<4;m++){
    int c = tid + m*256;
    acc[m] = (c < NCLS) ? logits[(size_t)b*NCLS + c] : -1e30f;
    mx = fmaxf(mx, acc[m]);
  }
  red[tid] = mx; __syncthreads();
  for (int o=128;o>0;o>>=1){ if (tid<o) red[tid] = fmaxf(red[tid], red[tid+o]); __syncthreads(); }
  mx = red[0]; __syncthreads();
  float ex[4]; float s = 0.f;
  #pragma unroll
  for (int m=0;m<4;m++){
    int c = tid + m*256;
    ex[m] = (c < NCLS) ? expf(acc[m]-mx) : 0.f;
    s += ex[m];
  }
  red[tid] = s; __syncthreads();
  for (int o=128;o>0;o>>=1){ if (tid<o) red[tid] += red[tid+o]; __syncthreads(); }
  float inv = 1.f / red[0];
  #pragma unroll
  for (int m=0;m<4;m++){
    int c = tid + m*256;
    if (c < NCLS) outp[(size_t)b*NCLS + c] = ex[m]*inv;
  }
}

// ================= host =================
extern "C" void kernel_launch(void* const* d_in, const int* in_sizes, int n_in,
                              void* d_out, int out_size, void* d_ws, size_t ws_size,
                              hipStream_t stream)
{
  const float* x      = (const float*)d_in[0];
  const float* W_emb  = (const float*)d_in[1];
  const float* b_emb  = (const float*)d_in[2];
  const float* v_class= (const float*)d_in[3];
  const float* ln1_g  = (const float*)d_in[4];
  const float* ln1_b  = (const float*)d_in[5];
  const float* Wq     = (const float*)d_in[6];
  const float* bq     = (const float*)d_in[7];
  const float* Wk     = (const float*)d_in[8];
  const float* bk     = (const float*)d_in[9];
  const float* Wv     = (const float*)d_in[10];
  const float* bv     = (const float*)d_in[11];
  const float* ln2_g  = (const float*)d_in[12];
  const float* ln2_b  = (const float*)d_in[13];
  const float* W1     = (const float*)d_in[14];
  const float* b1     = (const float*)d_in[15];
  const float* W2     = (const float*)d_in[16];
  const float* b2     = (const float*)d_in[17];
  const float* W_cls  = (const float*)d_in[18];
  const float* b_cls  = (const float*)d_in[19];
  (void)in_sizes; (void)n_in; (void)out_size;
  float* outp = (float*)d_out;

  char* ws = (char*)d_ws;
  size_t off = 0;
  auto alloc = [&](size_t bytes)->char*{
    char* p = ws + off;
    off = (off + bytes + 255) & ~((size_t)255);
    return p;
  };
  float* pos    = (float*)alloc((size_t)PP*DD*4);
  float* hbuf   = (float*)alloc((size_t)NTOK*DD*4);
  u16*   xnb    = (u16*)  alloc((size_t)NTOK*DD*2);
  float2* statsb= (float2*)alloc((size_t)NTOK*8);
  u16*   WembT  = (u16*)  alloc((size_t)DD*DD*2);
  u16*   W1Tall = (u16*)  alloc((size_t)NLAY*DD*DD4*2);
  u16*   W2Tall = (u16*)  alloc((size_t)NLAY*DD*DD4*2);
  u16*   WqT    = (u16*)  alloc((size_t)NLAY*HH*HDD*HDD*2);
  u16*   WkT    = (u16*)  alloc((size_t)NLAY*HH*HDD*HDD*2);
  u16*   WvT    = (u16*)  alloc((size_t)NLAY*HH*HDD*HDD*2);
  // blob: holds q/k/v/attn during attention phase, then fc1's m during MLP
  char*  blob   = alloc((size_t)NTOK*DD4*2);   // 38.7 MB (mbuf size, superset)
  float* logitsb= (float*)alloc((size_t)BB*NCLS*4);
  u16* qbuf = (u16*)blob;
  u16* kbuf = qbuf + (size_t)NBH*SS*HDD;
  u16* vbuf = kbuf + (size_t)NBH*SS*HDD;
  u16* scb  = vbuf + (size_t)NBH*KPAD*HDD;     // attn (bf16); ends ~32.7MB into blob
  u16* mbuf = (u16*)blob;                      // fc1 out, 38.7MB (q/k/v/attn dead by then)
  u16* xbf  = scb;                             // x bf16 (9.2MB); dead before layer-0 attn
  if (ws_size < off) return;    // all-zero output signals ws too small

  hipMemsetAsync(vbuf, 0, (size_t)NBH*KPAD*HDD*2, stream);  // NaN-proof pad rows
  pos_kernel<<<(PP*DD+255)/256, 256, 0, stream>>>(pos);
  f32_to_bf16_kernel<<<(NTOKX*DD/4+255)/256, 256, 0, stream>>>(x, xbf, NTOKX*DD/4);
  dim3 tb(32,8);
  transpose_kernel<<<dim3(DD/32, DD/32, 1), tb, 0, stream>>>(W_emb, WembT, DD, DD);
  transpose_kernel<<<dim3(2,2,NLAY*HH), tb, 0, stream>>>(Wq, WqT, HDD, HDD);
  transpose_kernel<<<dim3(2,2,NLAY*HH), tb, 0, stream>>>(Wk, WkT, HDD, HDD);
  transpose_kernel<<<dim3(2,2,NLAY*HH), tb, 0, stream>>>(Wv, WvT, HDD, HDD);
  // all-layer weight transposes hoisted out of the loop (z = layer)
  transpose_kernel<<<dim3(DD4/32, DD/32, NLAY), tb, 0, stream>>>(W1, W1Tall, DD, DD4);
  transpose_kernel<<<dim3(DD/32, DD4/32, NLAY), tb, 0, stream>>>(W2, W2Tall, DD4, DD);

  gemm_bf16<0><<<49*6, 256, 0, stream>>>(xbf, WembT, NTOKX, DD, 49, 6, b_emb, pos, hbuf, nullptr);
  clstok_kernel<<<BB, 256, 0, stream>>>(v_class, hbuf);

  for (int l=0; l<NLAY; ++l){
    ln_stats_kernel<<<NTOK/4, 256, 0, stream>>>(hbuf, statsb);
    qkv_kernel<<<dim3(50, HH), 256, 0, stream>>>(hbuf, statsb,
        ln1_g + l*DD, ln1_b + l*DD,
        WqT + (size_t)l*HH*4096, WkT + (size_t)l*HH*4096, WvT + (size_t)l*HH*4096,
        bq + l*HH*HDD, bk + l*HH*HDD, bv + l*HH*HDD, qbuf, kbuf, vbuf);
    attn_scores_softmax_kernel<<<dim3(2, NBH), 256, 0, stream>>>(qbuf, kbuf, scb);
    attnmean_kernel<<<dim3(SS, BB), 256, 0, stream>>>(scb, outp + 32000 + (size_t)l*BB*SS*SS);
    av_kernel<<<dim3(2, NBH), 256, 0, stream>>>(scb, vbuf, hbuf);
    ln_kernel<<<NTOK/4, 256, 0, stream>>>(hbuf, ln2_g + l*DD, ln2_b + l*DD, xnb);
    gemm_bf16<1><<<50*24, 256, 0, stream>>>(xnb, W1Tall + (size_t)l*DD*DD4, NTOK, DD, 50, 24,
                                            b1 + l*DD4, nullptr, nullptr, mbuf);
    gemm_bf16<2><<<50*6, 256, 0, stream>>>(mbuf, W2Tall + (size_t)l*DD*DD4, NTOK, DD4, 50, 6,
                                           b2 + l*DD, nullptr, hbuf, nullptr);
  }
  logits_kernel<<<dim3(BB, 4), 256, 0, stream>>>(hbuf, W_cls, b_cls, logitsb);
  pred_softmax_kernel<<<BB, 256, 0, stream>>>(logitsb, outp);
}